// Round 1
// baseline (561.412 us; speedup 1.0000x reference)
//
#include <hip/hip_runtime.h>
#include <hip/hip_bf16.h>
#include <stdint.h>

typedef __bf16 bf16;
typedef bf16 bf16x8 __attribute__((ext_vector_type(8)));
typedef float f32x4 __attribute__((ext_vector_type(4)));

// Load 8 consecutive elements as a bf16x8 MFMA operand pack.
__device__ __forceinline__ bf16x8 load8(const float* p) {
    const f32x4 lo = *(const f32x4*)p;
    const f32x4 hi = *(const f32x4*)(p + 4);
    bf16x8 v;
#pragma unroll
    for (int r = 0; r < 4; ++r) { v[r] = (bf16)lo[r]; v[4 + r] = (bf16)hi[r]; }
    return v;
}
__device__ __forceinline__ bf16x8 load8(const bf16* p) {
    return *(const bf16x8*)p;
}

// ---------------------------------------------------------------------------
// C[M,N] = A[M,K] @ B[N,K]^T   (fp32 accum; AT/BT in {float,bf16}; CT out)
// 128x128 tile, BK=32, 4 waves, each wave 64x64 (4x4 MFMAs). Register staging.
// ---------------------------------------------------------------------------
template <typename AT, typename BT, typename CT>
__global__ __launch_bounds__(256) void gemm_bt(const AT* __restrict__ A,
                                               const BT* __restrict__ B,
                                               CT* __restrict__ C,
                                               int M, int N, int K) {
    __shared__ __align__(16) bf16 As[128 * 32];
    __shared__ __align__(16) bf16 Bs[128 * 32];
    const int tid  = threadIdx.x;
    const int wave = tid >> 6, lane = tid & 63;
    const int quad = lane >> 4, l16 = lane & 15;
    const int m0 = blockIdx.y * 128, n0 = blockIdx.x * 128;
    const int wr = (wave >> 1) * 64, wc = (wave & 1) * 64;

    const int srow = wave * 32 + (lane >> 2);
    const int scol = (lane & 3) * 8;
    const AT* Ag = A + (size_t)(m0 + srow) * K + scol;
    const BT* Bg = B + (size_t)(n0 + srow) * K + scol;
    bf16* Asw = &As[srow * 32 + scol];
    bf16* Bsw = &Bs[srow * 32 + scol];

    f32x4 acc[4][4] = {};

    for (int k0 = 0; k0 < K; k0 += 32) {
        const bf16x8 av0 = load8(Ag + k0);
        const bf16x8 av1 = load8(Ag + k0 + (size_t)16 * K);
        const bf16x8 bv0 = load8(Bg + k0);
        const bf16x8 bv1 = load8(Bg + k0 + (size_t)16 * K);
        __syncthreads();
        *(bf16x8*)(Asw)           = av0;
        *(bf16x8*)(Asw + 16 * 32) = av1;
        *(bf16x8*)(Bsw)           = bv0;
        *(bf16x8*)(Bsw + 16 * 32) = bv1;
        __syncthreads();

        bf16x8 a[4], b[4];
#pragma unroll
        for (int i = 0; i < 4; ++i)
            a[i] = *(const bf16x8*)&As[(wr + i * 16 + l16) * 32 + quad * 8];
#pragma unroll
        for (int j = 0; j < 4; ++j)
            b[j] = *(const bf16x8*)&Bs[(wc + j * 16 + l16) * 32 + quad * 8];
#pragma unroll
        for (int i = 0; i < 4; ++i)
#pragma unroll
            for (int j = 0; j < 4; ++j)
                acc[i][j] = __builtin_amdgcn_mfma_f32_16x16x32_bf16(a[i], b[j], acc[i][j], 0, 0, 0);
    }

#pragma unroll
    for (int i = 0; i < 4; ++i)
#pragma unroll
        for (int j = 0; j < 4; ++j) {
            const int row = m0 + wr + i * 16 + quad * 4;
            const int col = n0 + wc + j * 16 + l16;
#pragma unroll
            for (int r = 0; r < 4; ++r)
                C[(size_t)(row + r) * N + col] = (CT)acc[i][j][r];
        }
}

// ---------------------------------------------------------------------------
// RMSNorm + RoPE (theta=1e6, half=128), in place on bf16; fp32 weights.
// ---------------------------------------------------------------------------
__global__ __launch_bounds__(256) void norm_rope(bf16* __restrict__ x,
                                                 const float* __restrict__ w,
                                                 int L, int div) {
    const int row = blockIdx.x;
    const int t = threadIdx.x;
    const size_t base = (size_t)row * 256;

    const float v = (float)x[base + t];
    float ss = v * v;
#pragma unroll
    for (int off = 32; off >= 1; off >>= 1) ss += __shfl_xor(ss, off);

    __shared__ float wsum[4];
    __shared__ float buf[256];
    const int wave = t >> 6, lane = t & 63;
    if (lane == 0) wsum[wave] = ss;
    __syncthreads();
    const float var = (wsum[0] + wsum[1] + wsum[2] + wsum[3]) * (1.0f / 256.0f);
    const float inv = rsqrtf(var + 1e-6f);
    buf[t] = v * inv * w[t];
    __syncthreads();

    const int pos = (row / div) % L;
    const int i = t & 127;
    const float freq = (float)pos * exp2f(-(float)i * (19.93156857f / 128.0f));
    const float c = cosf(freq), s = sinf(freq);
    const float x1 = buf[i], x2 = buf[i + 128];
    const float out = (t < 128) ? (x1 * c - x2 * s) : (x1 * s + x2 * c);
    x[base + t] = (bf16)out;
}

// ---------------------------------------------------------------------------
// Vt[b][d][l] = V[b][l][d]
// ---------------------------------------------------------------------------
__global__ __launch_bounds__(256) void transpose_v(const bf16* __restrict__ V,
                                                   bf16* __restrict__ Vt, int L) {
    __shared__ bf16 tile[32][33];
    const int b = blockIdx.z;
    const int l0 = blockIdx.x * 32, d0 = blockIdx.y * 32;
    const int tx = threadIdx.x & 31, ty = threadIdx.x >> 5;
#pragma unroll
    for (int i = 0; i < 32; i += 8)
        tile[ty + i][tx] = V[((size_t)b * L + l0 + ty + i) * 256 + d0 + tx];
    __syncthreads();
#pragma unroll
    for (int i = 0; i < 32; i += 8)
        Vt[((size_t)b * 256 + d0 + ty + i) * L + l0 + tx] = tile[tx][ty + i];
}

// ---------------------------------------------------------------------------
// Causal MQA flash attention, v3.
// v2 was latency-bound: 256 blocks x 4 waves = 1 wave/SIMD (Occupancy 11%,
// MfmaUtil 11%, every dep chain exposed). Total wave count is fixed at
// B*H*L/16 = 2048 waves; to get them all resident (2/SIMD) while keeping the
// pair-trick's perfect balance, each block is now 8 waves: two 4-wave groups
// split the KV range of each q-tile (group0: kt in [0,s/2), group1: the rest
// incl. the diagonal), each group staging its own K/V tile in its own LDS
// half. Partial (O,m,l) states merge through LDS at end of each pass.
// - Block z still handles q-tiles {nqt-1-z, z}: exactly nqt+1 KV steps/block.
// - LDS 159,744 B dynamic -> 1 block/CU = 8 waves/CU = 2 waves/SIMD; waves
//   0-3 (group0) and 4-7 (group1) land one-per-SIMD -> each SIMD co-schedules
//   two waves at different phases (staging/softmax vs MFMA).
// - Merge buffer (64x260 f32 + m,l) aliases the K region (dead at merge time;
//   next pass's first barrier orders reuse).
// ---------------------------------------------------------------------------
__global__ __launch_bounds__(512, 2) void flash_attn(const bf16* __restrict__ Q,
                                                     const bf16* __restrict__ K,
                                                     const bf16* __restrict__ Vt,
                                                     bf16* __restrict__ Ctx, int L) {
    constexpr int H = 8, HD = 256;
    constexpr int KSTR = 264, VSTR = 72, PSTR = 72, OSTR = 260;
    extern __shared__ __align__(16) bf16 smem[];
    const int tid = threadIdx.x;
    const int wave = tid >> 6, lane = tid & 63;
    const int g = wave >> 2, w = wave & 3;   // group, row-wave within group
    const int quad = lane >> 4, l16 = lane & 15;

    bf16* Ksg = smem + g * 64 * KSTR;                      // my group's K tile
    bf16* Vsg = smem + 2 * 64 * KSTR + g * 256 * VSTR;     // my group's V tile
    bf16* Pw  = smem + 2 * 64 * KSTR + 2 * 256 * VSTR + wave * 16 * PSTR;
    float* mergeO  = (float*)smem;                         // 64 x OSTR f32 (aliases K region)
    float* mergeML = mergeO + 64 * OSTR;                   // 64 x {m,l}

    const int z = blockIdx.x, h = blockIdx.y, b = blockIdx.z;
    const int nqt = L / 64;

    const bf16* Kb = K + (size_t)b * L * HD;
    const bf16* Vb = Vt + (size_t)b * HD * L;

    // cooperative staging maps within the 256-thread group
    const int gtid = tid & 255;
    const int krow = gtid >> 5, kcol = (gtid & 31) * 8;
    const int vrow = gtid >> 3, vcol = (gtid & 7) * 8;

    for (int pass = 0; pass < 2; ++pass) {
        const int qt = pass ? z : (nqt - 1 - z);
        const int q0 = qt * 64 + w * 16;
        const int s  = qt + 1;          // total KV tiles for this q-tile
        const int h0 = s >> 1;          // group0 tile count
        const int n1 = s - h0;          // group1 tile count = loop trips
        const int ktbase  = g ? h0 : 0;
        const int mycount = g ? n1 : h0;

        // Q fragments: A-operand layout A[m=l16][k=quad*8+j], k-chunks of 32
        bf16x8 qf[8];
        {
            const bf16* qbase = Q + ((size_t)(b * L + q0 + l16) * H + h) * HD + quad * 8;
#pragma unroll
            for (int kc = 0; kc < 8; ++kc) qf[kc] = *(const bf16x8*)(qbase + kc * 32);
        }

        f32x4 Oacc[16] = {};
        float mrow[4], lrow[4];
#pragma unroll
        for (int r = 0; r < 4; ++r) { mrow[r] = -1e30f; lrow[r] = 0.0f; }

        bf16x8 kreg[8], vreg[8];
        // prologue: load my group's first tile into registers
        if (mycount > 0) {
            const int kv0 = ktbase * 64;
#pragma unroll
            for (int i = 0; i < 8; ++i)
                kreg[i] = *(const bf16x8*)(Kb + (size_t)(kv0 + i * 8 + krow) * HD + kcol);
#pragma unroll
            for (int i = 0; i < 8; ++i)
                vreg[i] = *(const bf16x8*)(Vb + (size_t)(i * 32 + vrow) * L + kv0 + vcol);
        }
        __syncthreads();  // B0: previous pass's merge reads done -> LDS reusable
        if (mycount > 0) {
#pragma unroll
            for (int i = 0; i < 8; ++i)
                *(bf16x8*)&Ksg[(i * 8 + krow) * KSTR + kcol] = kreg[i];
#pragma unroll
            for (int i = 0; i < 8; ++i)
                *(bf16x8*)&Vsg[(i * 32 + vrow) * VSTR + vcol] = vreg[i];
        }
        __syncthreads();  // B1: staged tile visible

        for (int it = 0; it < n1; ++it) {
            const int kt = ktbase + it;
            const int kv0 = kt * 64;
            const bool active = it < mycount;
            const bool more   = (it + 1) < mycount;
            if (more) {  // prefetch next tile into registers (overlaps compute)
                const int nv0 = kv0 + 64;
#pragma unroll
                for (int i = 0; i < 8; ++i)
                    kreg[i] = *(const bf16x8*)(Kb + (size_t)(nv0 + i * 8 + krow) * HD + kcol);
#pragma unroll
                for (int i = 0; i < 8; ++i)
                    vreg[i] = *(const bf16x8*)(Vb + (size_t)(i * 32 + vrow) * L + nv0 + vcol);
            }

            if (active) {
                // ---- S = Q K^T from LDS (two independent accum chains) ----
                f32x4 S[4];
#pragma unroll
                for (int nt = 0; nt < 4; ++nt) {
                    f32x4 slo = {0.f, 0.f, 0.f, 0.f}, shi = {0.f, 0.f, 0.f, 0.f};
                    const bf16* kb = &Ksg[(nt * 16 + l16) * KSTR + quad * 8];
#pragma unroll
                    for (int kc = 0; kc < 4; ++kc)
                        slo = __builtin_amdgcn_mfma_f32_16x16x32_bf16(qf[kc], *(const bf16x8*)(kb + kc * 32), slo, 0, 0, 0);
#pragma unroll
                    for (int kc = 4; kc < 8; ++kc)
                        shi = __builtin_amdgcn_mfma_f32_16x16x32_bf16(qf[kc], *(const bf16x8*)(kb + kc * 32), shi, 0, 0, 0);
                    S[nt] = slo + shi;
                }

                // ---- scale + causal mask (diag tile only) + row max ----
                float rowmax[4] = {-1e30f, -1e30f, -1e30f, -1e30f};
                const bool diag = (kt == qt);
#pragma unroll
                for (int nt = 0; nt < 4; ++nt) {
                    const int col = kv0 + nt * 16 + l16;
#pragma unroll
                    for (int r = 0; r < 4; ++r) {
                        float sv = S[nt][r] * 0.0625f;  // 1/sqrt(256)
                        if (diag && col > q0 + quad * 4 + r) sv = -1e30f;
                        S[nt][r] = sv;
                        rowmax[r] = fmaxf(rowmax[r], sv);
                    }
                }
#pragma unroll
                for (int off = 1; off < 16; off <<= 1)
#pragma unroll
                    for (int r = 0; r < 4; ++r)
                        rowmax[r] = fmaxf(rowmax[r], __shfl_xor(rowmax[r], off));

                // ---- online softmax ----
                float alpha[4], rsum[4];
#pragma unroll
                for (int r = 0; r < 4; ++r) {
                    const float mnew = fmaxf(mrow[r], rowmax[r]);
                    alpha[r] = __expf(mrow[r] - mnew);
                    mrow[r] = mnew;
                    rsum[r] = 0.0f;
                }
#pragma unroll
                for (int nt = 0; nt < 4; ++nt)
#pragma unroll
                    for (int r = 0; r < 4; ++r) {
                        const float p = __expf(S[nt][r] - mrow[r]);
                        rsum[r] += p;
                        Pw[(quad * 4 + r) * PSTR + nt * 16 + l16] = (bf16)p;  // C-layout
                    }
#pragma unroll
                for (int off = 1; off < 16; off <<= 1)
#pragma unroll
                    for (int r = 0; r < 4; ++r) rsum[r] += __shfl_xor(rsum[r], off);
#pragma unroll
                for (int r = 0; r < 4; ++r) lrow[r] = lrow[r] * alpha[r] + rsum[r];

                // ---- rescale O, then O += P V from LDS ----
#pragma unroll
                for (int nt = 0; nt < 16; ++nt)
#pragma unroll
                    for (int r = 0; r < 4; ++r) Oacc[nt][r] *= alpha[r];

                bf16x8 pf[2];
#pragma unroll
                for (int ks = 0; ks < 2; ++ks)
                    pf[ks] = *(const bf16x8*)&Pw[l16 * PSTR + ks * 32 + quad * 8];
#pragma unroll
                for (int nt = 0; nt < 16; ++nt) {
                    const bf16* vb2 = &Vsg[(nt * 16 + l16) * VSTR + quad * 8];
                    f32x4 o = Oacc[nt];
#pragma unroll
                    for (int ks = 0; ks < 2; ++ks)
                        o = __builtin_amdgcn_mfma_f32_16x16x32_bf16(pf[ks], *(const bf16x8*)(vb2 + ks * 32), o, 0, 0, 0);
                    Oacc[nt] = o;
                }
            }

            __syncthreads();  // B2: all reads of current LDS tiles done
            if (more) {
#pragma unroll
                for (int i = 0; i < 8; ++i)
                    *(bf16x8*)&Ksg[(i * 8 + krow) * KSTR + kcol] = kreg[i];
#pragma unroll
                for (int i = 0; i < 8; ++i)
                    *(bf16x8*)&Vsg[(i * 32 + vrow) * VSTR + vcol] = vreg[i];
            }
            __syncthreads();  // B3: staged tile visible
        }

        // ---- merge group1's partial state into group0, group0 stores ----
        if (g == 1) {
            if (l16 == 0) {
#pragma unroll
                for (int r = 0; r < 4; ++r) {
                    const int row = w * 16 + quad * 4 + r;
                    mergeML[row * 2 + 0] = mrow[r];
                    mergeML[row * 2 + 1] = lrow[r];
                }
            }
#pragma unroll
            for (int nt = 0; nt < 16; ++nt)
#pragma unroll
                for (int r = 0; r < 4; ++r)
                    mergeO[(w * 16 + quad * 4 + r) * OSTR + nt * 16 + l16] = Oacc[nt][r];
        }
        __syncthreads();  // B4: group1 partial state visible
        if (g == 0) {
            float a0[4], a1[4], linv[4];
#pragma unroll
            for (int r = 0; r < 4; ++r) {
                const int row = w * 16 + quad * 4 + r;
                const float m1 = mergeML[row * 2 + 0];
                const float l1 = mergeML[row * 2 + 1];
                const float mn = fmaxf(mrow[r], m1);
                a0[r] = __expf(mrow[r] - mn);
                a1[r] = __expf(m1 - mn);
                linv[r] = 1.0f / (lrow[r] * a0[r] + l1 * a1[r]);
            }
            bf16* obase = Ctx + ((size_t)(b * L + q0) * H + h) * HD;
#pragma unroll
            for (int nt = 0; nt < 16; ++nt)
#pragma unroll
                for (int r = 0; r < 4; ++r) {
                    const int row = w * 16 + quad * 4 + r;
                    const float o1 = mergeO[row * OSTR + nt * 16 + l16];
                    const float val = (Oacc[nt][r] * a0[r] + o1 * a1[r]) * linv[r];
                    obase[(size_t)(quad * 4 + r) * (H * HD) + nt * 16 + l16] = (bf16)val;
                }
        }
        // next pass's B0 orders merge-region reuse as K-tile storage
    }
}

// ---------------------------------------------------------------------------
extern "C" void kernel_launch(void* const* d_in, const int* in_sizes, int n_in,
                              void* d_out, int out_size, void* d_ws, size_t ws_size,
                              hipStream_t stream) {
    const float* x      = (const float*)d_in[0];
    const float* q_proj = (const float*)d_in[1];
    const float* k_proj = (const float*)d_in[2];
    const float* v_proj = (const float*)d_in[3];
    const float* o_proj = (const float*)d_in[4];
    const float* q_norm = (const float*)d_in[5];
    const float* k_norm = (const float*)d_in[6];
    float* out = (float*)d_out;

    constexpr int B = 2, L = 2048, D = 2048, H = 8, HD = 256;
    constexpr int M = B * L;  // 4096
    // 2 K-tiles + 2 V-tiles + 8 P: (2*64*264 + 2*256*72 + 8*16*72) elems * 2B
    constexpr int FLASH_LDS = (2 * 64 * 264 + 2 * 256 * 72 + 8 * 16 * 72) * 2;  // 159,744 B

    static bool attr_set = false;  // host-side once; same device work every call
    if (!attr_set) {
        (void)hipFuncSetAttribute((const void*)flash_attn,
                                  hipFuncAttributeMaxDynamicSharedMemorySize, FLASH_LDS);
        attr_set = true;
    }

    bf16* Qw  = (bf16*)d_ws;                 // M * D      (B,L,H,HD)
    bf16* Kw  = Qw  + (size_t)M * D;         // M * HD     (B,L,HD)
    bf16* Vw  = Kw  + (size_t)M * HD;        // M * HD
    bf16* Vtw = Vw  + (size_t)M * HD;        // B * HD * L
    bf16* Ctx = Vtw + (size_t)M * HD;        // M * D

    gemm_bt<float, float, bf16><<<dim3(D / 128, M / 128), 256, 0, stream>>>(x, q_proj, Qw, M, D, D);
    gemm_bt<float, float, bf16><<<dim3(HD / 128, M / 128), 256, 0, stream>>>(x, k_proj, Kw, M, HD, D);
    gemm_bt<float, float, bf16><<<dim3(HD / 128, M / 128), 256, 0, stream>>>(x, v_proj, Vw, M, HD, D);
    norm_rope<<<M * H, 256, 0, stream>>>(Qw, q_norm, L, H);
    norm_rope<<<M, 256, 0, stream>>>(Kw, k_norm, L, 1);
    transpose_v<<<dim3(L / 32, HD / 32, B), 256, 0, stream>>>(Vw, Vtw, L);
    flash_attn<<<dim3(L / 128, H, B), 512, FLASH_LDS, stream>>>(Qw, Kw, Vtw, Ctx, L);
    gemm_bt<bf16, float, float><<<dim3(D / 128, M / 128), 256, 0, stream>>>(Ctx, o_proj, out, M, D, D);
}